// Round 2
// baseline (2222.832 us; speedup 1.0000x reference)
//
#include <hip/hip_runtime.h>
#include <math.h>
#include <stdint.h>

#define B_ 8
#define T_ 2048
#define D_ 1024
#define H_ 1365
#define NTOK (B_*T_)
#define NSAMP 5
#define NRHO 5

// ---- ws layout (bytes) ----
#define WS_SCORES 0                              // f64 [16384]
#define WS_CNT    (WS_SCORES + NTOK*8)           // int [5*8*2048]
#define WS_PREDW  (WS_CNT + NRHO*B_*T_*4)        // f64 [5][8][1024]
#define WS_FULLW  (WS_PREDW + NRHO*B_*D_*8)      // f64 [8][1024]
#define WS_SUMEFF (WS_FULLW + B_*D_*8)           // f64 [5][8]
#define WS_SUMATT (WS_SUMEFF + NRHO*B_*8)        // f64 [8]
#define WS_SUMG   (WS_SUMATT + B_*8)             // f64 [5][8]
#define WS_ZERO_BYTES (WS_SUMG + NRHO*B_*8)

// ---- out layout (f32 elements) ----
#define OUT_G      0
#define OUT_GSW    16384
#define OUT_RECON  98304
#define OUT_LOSS   98305
#define OUT_RHOEFF 98310

// ============================================================
// Kernel A: fused LN + GEMM(D->H) + GELU + dot(W2) -> scores (f64 atomic accum)
// block = 256 threads; tile = 64 tokens x 64 h; K-chunks of 32, f64 accumulate
// ============================================================
__launch_bounds__(256)
__global__ void k_scores(const float* __restrict__ emb, const float* __restrict__ attn,
                         const float* __restrict__ ln_g, const float* __restrict__ ln_b,
                         const float* __restrict__ W1, const float* __restrict__ b1,
                         const float* __restrict__ W2, double* __restrict__ scores)
{
    __shared__ double sA[32][66];   // [k][tok], padded
    __shared__ double sW[32][64];   // [k][h]
    __shared__ double sM[64], sI[64];
    __shared__ double sRed[64][16];

    const int tid = threadIdx.x;
    const int t0  = blockIdx.y * 64;   // token block
    const int h0  = blockIdx.x * 64;   // h block

    // ---- phase 1: LN stats for the 64 tokens (f64) ----
    {
        const int wid = tid >> 6, lane = tid & 63;
        for (int tk = wid; tk < 64; tk += 4) {
            const int tg = t0 + tk;
            const float av = attn[tg];
            const float* row = emb + (size_t)tg * D_;
            double s1 = 0.0, s2 = 0.0;
            #pragma unroll
            for (int i = 0; i < D_/64; ++i) {
                double x = (double)row[i*64 + lane] * (double)av;
                s1 += x; s2 += x * x;
            }
            for (int m = 32; m; m >>= 1) { s1 += __shfl_xor(s1, m); s2 += __shfl_xor(s2, m); }
            if (lane == 0) {
                double mean = s1 / (double)D_;
                double var  = s2 / (double)D_ - mean * mean;
                sM[tk] = mean;
                sI[tk] = 1.0 / sqrt(var + 1e-5);
            }
        }
    }
    __syncthreads();

    double acc[4][4];
    #pragma unroll
    for (int i = 0; i < 4; ++i)
        #pragma unroll
        for (int j = 0; j < 4; ++j) acc[i][j] = 0.0;

    const int tx = tid & 15, tyg = tid >> 4;

    for (int kc = 0; kc < D_; kc += 32) {
        // stage W1 tile [k][h]
        #pragma unroll
        for (int r = 0; r < 8; ++r) {
            int e = tid + r * 256;
            int k = e >> 6, h = e & 63;
            int hg = h0 + h;
            float w = (hg < H_) ? W1[(size_t)(kc + k) * H_ + hg] : 0.0f;
            sW[k][h] = (double)w;
        }
        // stage LN(A) tile [k][tok]
        #pragma unroll
        for (int r = 0; r < 8; ++r) {
            int e = tid + r * 256;
            int k = e & 31, tk = e >> 5;
            int tg = t0 + tk, dg = kc + k;
            double x  = (double)emb[(size_t)tg * D_ + dg] * (double)attn[tg];
            double xn = (x - sM[tk]) * sI[tk] * (double)ln_g[dg] + (double)ln_b[dg];
            sA[k][tk] = xn;
        }
        __syncthreads();
        #pragma unroll
        for (int k = 0; k < 32; ++k) {
            double a0 = sA[k][tyg*4+0], a1 = sA[k][tyg*4+1],
                   a2 = sA[k][tyg*4+2], a3 = sA[k][tyg*4+3];
            double w0 = sW[k][tx*4+0], w1 = sW[k][tx*4+1],
                   w2 = sW[k][tx*4+2], w3 = sW[k][tx*4+3];
            acc[0][0] = fma(a0, w0, acc[0][0]); acc[0][1] = fma(a0, w1, acc[0][1]);
            acc[0][2] = fma(a0, w2, acc[0][2]); acc[0][3] = fma(a0, w3, acc[0][3]);
            acc[1][0] = fma(a1, w0, acc[1][0]); acc[1][1] = fma(a1, w1, acc[1][1]);
            acc[1][2] = fma(a1, w2, acc[1][2]); acc[1][3] = fma(a1, w3, acc[1][3]);
            acc[2][0] = fma(a2, w0, acc[2][0]); acc[2][1] = fma(a2, w1, acc[2][1]);
            acc[2][2] = fma(a2, w2, acc[2][2]); acc[2][3] = fma(a2, w3, acc[2][3]);
            acc[3][0] = fma(a3, w0, acc[3][0]); acc[3][1] = fma(a3, w1, acc[3][1]);
            acc[3][2] = fma(a3, w2, acc[3][2]); acc[3][3] = fma(a3, w3, acc[3][3]);
        }
        __syncthreads();
    }

    // ---- epilogue: gelu(z + b1) * W2, reduce over h ----
    const double inv_sqrt2 = 0.70710678118654752440;
    #pragma unroll
    for (int i = 0; i < 4; ++i) {
        double p = 0.0;
        #pragma unroll
        for (int j = 0; j < 4; ++j) {
            int hg = h0 + tx * 4 + j;
            if (hg < H_) {
                double z  = acc[i][j] + (double)b1[hg];
                double gl = 0.5 * z * (1.0 + erf(z * inv_sqrt2));
                p += gl * (double)W2[hg];
            }
        }
        sRed[tyg * 4 + i][tx] = p;
    }
    __syncthreads();
    if (tid < 64) {
        double s = 0.0;
        #pragma unroll
        for (int x = 0; x < 16; ++x) s += sRed[tid][x];
        atomicAdd(&scores[t0 + tid], s);
    }
}

// ============================================================
// JAX threefry2x32 (matches jax._src.prng exactly)
// ============================================================
__device__ inline void tf2x32(uint32_t k0, uint32_t k1, uint32_t x0, uint32_t x1,
                              uint32_t& o0, uint32_t& o1)
{
    const uint32_t ks2 = k0 ^ k1 ^ 0x1BD11BDAu;
    x0 += k0; x1 += k1;
#define ROT_(v,d) (((v) << (d)) | ((v) >> (32 - (d))))
#define RND_(R) { x0 += x1; x1 = ROT_(x1, R); x1 ^= x0; }
    RND_(13) RND_(15) RND_(26) RND_(6)
    x0 += k1;  x1 += ks2 + 1u;
    RND_(17) RND_(29) RND_(16) RND_(24)
    x0 += ks2; x1 += k0 + 2u;
    RND_(13) RND_(15) RND_(26) RND_(6)
    x0 += k0;  x1 += k1 + 3u;
    RND_(17) RND_(29) RND_(16) RND_(24)
    x0 += k1;  x1 += ks2 + 4u;
    RND_(13) RND_(15) RND_(26) RND_(6)
    x0 += ks2; x1 += k0 + 5u;
    o0 = x0; o1 = x1;
#undef RND_
#undef ROT_
}

// ============================================================
// Kernel B: per (rho j, sample s, batch b): gumbel pert + bitonic sort +
//           k-th threshold + indicator count accumulation
//
// RNG: JAX >= 0.4.36 default (jax_threefry_partitionable=True):
//   bits[f] = o0 ^ o1 where (o0,o1) = threefry2x32(key_j, hi32(f)=0, lo32(f)=f)
// ============================================================
__launch_bounds__(256)
__global__ void k_topk(const double* __restrict__ scores, const float* __restrict__ attn,
                       const float* __restrict__ b2, int* __restrict__ cnt)
{
    __shared__ double pertO[2048];
    __shared__ double psort[2048];
    __shared__ double red[4];

    const int tid = threadIdx.x;
    const int blk = blockIdx.x;
    const int j = blk / 40;
    const int s = (blk % 40) >> 3;
    const int b = blk & 7;

    // key_j = fold_in(key(42), j) = threefry((0,42),(0,j))  [mode-independent]
    uint32_t kk0, kk1;
    tf2x32(0u, 42u, 0u, (uint32_t)j, kk0, kk1);

    // T_eff
    double tsum = 0.0;
    for (int t = tid; t < T_; t += 256) tsum += (double)attn[b * T_ + t];
    for (int m = 32; m; m >>= 1) tsum += __shfl_xor(tsum, m);
    if ((tid & 63) == 0) red[tid >> 6] = tsum;
    __syncthreads();
    const double Teff = red[0] + red[1] + red[2] + red[3];
    const float rhos[5] = {0.1f, 0.2f, 0.3f, 0.4f, 0.5f};
    int kst = (int)(rhos[j] * (float)Teff);
    if (kst < 1) kst = 1;

    const double bb2 = (double)b2[0];
    for (int t = tid; t < T_; t += 256) {
        int f = (s * 8 + b) * T_ + t;   // flat index into (5,8,2048)
        uint32_t o0, o1;
        tf2x32(kk0, kk1, 0u, (uint32_t)f, o0, o1);   // partitionable: (hi,lo)=(0,f)
        uint32_t bits = o0 ^ o1;                     // 32-bit path: xor of both words
        // uniform: bitcast((bits>>9)|0x3f800000) - 1.0f
        float u = __uint_as_float((bits >> 9) | 0x3f800000u) - 1.0f;
        // f32 rounding chain of -log(-log(u+1e-6)+1e-6), correctly-rounded steps
        float a1 = (float)((double)u + (double)1e-6f);
        float la = (float)log((double)a1);
        float m1 = (float)((double)1e-6f - (double)la);
        float lb = (float)log((double)m1);
        float noise = -lb;
        float av = attn[b * T_ + t];
        double pv = (av == 0.0f) ? -1e9 : (scores[b * T_ + t] + bb2 + (double)noise);
        pertO[t] = pv;
        psort[t] = pv;
    }
    __syncthreads();

    // bitonic ascending sort of 2048 doubles
    for (int size = 2; size <= 2048; size <<= 1) {
        for (int stride = size >> 1; stride > 0; stride >>= 1) {
            for (int i = tid; i < 2048; i += 256) {
                int l = i ^ stride;
                if (l > i) {
                    double x = psort[i], y = psort[l];
                    bool asc = ((i & size) == 0);
                    if ((x > y) == asc) { psort[i] = y; psort[l] = x; }
                }
            }
            __syncthreads();
        }
    }
    const double thr = psort[2048 - kst];  // k-th largest
    for (int t = tid; t < T_; t += 256) {
        if (pertO[t] >= thr) atomicAdd(&cnt[(j * 8 + b) * T_ + t], 1);
    }
}

// ============================================================
// Kernel C: finalize g = cnt/5, write g & g_sweep & rho_eff, row sums
// ============================================================
__launch_bounds__(256)
__global__ void k_gfin(const int* __restrict__ cnt, const float* __restrict__ attn,
                       float* __restrict__ out, double* __restrict__ sumeff,
                       double* __restrict__ sumatt, double* __restrict__ sumg)
{
    __shared__ double redA[4], redB[4], redC[4];
    const int j = blockIdx.x >> 3, b = blockIdx.x & 7;
    const int tid = threadIdx.x;
    double sg = 0.0, se = 0.0, sa = 0.0;
    for (int t = tid; t < T_; t += 256) {
        int c = cnt[(j * 8 + b) * T_ + t];
        float g  = (float)c / 5.0f;
        float av = attn[b * T_ + t];
        out[OUT_GSW + (j * 8 + b) * T_ + t] = g;
        if (j == 4) out[OUT_G + b * T_ + t] = g;
        sg += (double)g;
        se += (double)(av * g);
        sa += (double)av;
    }
    for (int m = 32; m; m >>= 1) { sg += __shfl_xor(sg, m); se += __shfl_xor(se, m); sa += __shfl_xor(sa, m); }
    if ((tid & 63) == 0) { redA[tid>>6] = sg; redB[tid>>6] = se; redC[tid>>6] = sa; }
    __syncthreads();
    if (tid == 0) {
        sg = redA[0]+redA[1]+redA[2]+redA[3];
        se = redB[0]+redB[1]+redB[2]+redB[3];
        sa = redC[0]+redC[1]+redC[2]+redC[3];
        sumg[j*8+b] = sg; sumeff[j*8+b] = se;
        if (j == 0) sumatt[b] = sa;
        out[OUT_RHOEFF + j*8 + b] = (float)sg / (float)sa;   // g.sum(1)/T_eff
    }
}

// ============================================================
// Kernel D: pooled weighted sums over tok = emb_table[ids]
// ============================================================
__launch_bounds__(256)
__global__ void k_pool(const int* __restrict__ ids, const float* __restrict__ attn,
                       const float* __restrict__ out, const float* __restrict__ emb_table,
                       double* __restrict__ predw, double* __restrict__ fullw)
{
    __shared__ int   sid[256];
    __shared__ float sw[6][256];
    const int blk = blockIdx.x;
    const int b  = blk >> 5;
    const int dc = (blk >> 3) & 3;
    const int tc = blk & 7;
    const int tid = threadIdx.x;
    const int d = dc * 256 + tid;
    {
        int t = tc * 256 + tid;
        sid[tid] = ids[b * T_ + t];
        float av = attn[b * T_ + t];
        sw[0][tid] = av;
        #pragma unroll
        for (int j = 0; j < 5; ++j) {
            float g = out[OUT_GSW + (j * 8 + b) * T_ + t];
            sw[1 + j][tid] = av * g;
        }
    }
    __syncthreads();
    double acc[6] = {0,0,0,0,0,0};
    for (int i = 0; i < 256; ++i) {
        float val = emb_table[(size_t)sid[i] * D_ + d];
        #pragma unroll
        for (int c = 0; c < 6; ++c) acc[c] += (double)(val * sw[c][i]);
    }
    atomicAdd(&fullw[b * D_ + d], acc[0]);
    #pragma unroll
    for (int j = 0; j < 5; ++j)
        atomicAdd(&predw[(j * 8 + b) * D_ + d], acc[1 + j]);
}

// ============================================================
// Kernel E: losses (single block)
// ============================================================
__launch_bounds__(256)
__global__ void k_loss(const double* __restrict__ predw, const double* __restrict__ fullw,
                       const double* __restrict__ sumeff, const double* __restrict__ sumatt,
                       float* __restrict__ out)
{
    __shared__ double red[4];
    __shared__ float lr[5];
    const int tid = threadIdx.x;
    for (int j = 0; j < 5; ++j) {
        double p = 0.0;
        for (int i = tid; i < B_ * D_; i += 256) {
            int b = i >> 10;
            double dF = sumatt[b];        if (dF < 1e-6) dF = 1e-6;
            double dE = sumeff[j*8 + b];  if (dE < 1e-6) dE = 1e-6;
            double diff = predw[j * B_ * D_ + i] / dE - fullw[i] / dF;
            p += diff * diff;
        }
        for (int m = 32; m; m >>= 1) p += __shfl_xor(p, m);
        if ((tid & 63) == 0) red[tid >> 6] = p;
        __syncthreads();
        if (tid == 0) {
            double t = red[0] + red[1] + red[2] + red[3];
            lr[j] = (float)(t / (double)(B_ * D_));
            out[OUT_LOSS + j] = lr[j];
        }
        __syncthreads();
    }
    if (tid == 0) {
        float srec = 0.0f;
        for (int j = 0; j < 5; ++j) srec += lr[j];   // f32 sequential like ref
        out[OUT_RECON] = srec / 5.0f;
    }
}

extern "C" void kernel_launch(void* const* d_in, const int* in_sizes, int n_in,
                              void* d_out, int out_size, void* d_ws, size_t ws_size,
                              hipStream_t stream)
{
    const int*   ids  = (const int*)  d_in[0];
    const float* emb  = (const float*)d_in[1];
    const float* attn = (const float*)d_in[2];
    const float* ln_g = (const float*)d_in[3];
    const float* ln_b = (const float*)d_in[4];
    const float* W1   = (const float*)d_in[5];
    const float* b1   = (const float*)d_in[6];
    const float* W2   = (const float*)d_in[7];
    const float* b2   = (const float*)d_in[8];
    const float* et   = (const float*)d_in[9];
    float* out = (float*)d_out;
    char*  ws  = (char*)d_ws;

    double* scores = (double*)(ws + WS_SCORES);
    int*    cnt    = (int*)   (ws + WS_CNT);
    double* predw  = (double*)(ws + WS_PREDW);
    double* fullw  = (double*)(ws + WS_FULLW);
    double* sumeff = (double*)(ws + WS_SUMEFF);
    double* sumatt = (double*)(ws + WS_SUMATT);
    double* sumg   = (double*)(ws + WS_SUMG);

    hipMemsetAsync(d_ws, 0, WS_ZERO_BYTES, stream);

    dim3 gA(22, 256);   // 22 h-blocks x 256 token-blocks
    k_scores<<<gA, 256, 0, stream>>>(emb, attn, ln_g, ln_b, W1, b1, W2, scores);
    k_topk<<<NRHO * NSAMP * B_, 256, 0, stream>>>(scores, attn, b2, cnt);
    k_gfin<<<NRHO * B_, 256, 0, stream>>>(cnt, attn, out, sumeff, sumatt, sumg);
    k_pool<<<256, 256, 0, stream>>>(ids, attn, out, et, predw, fullw);
    k_loss<<<1, 256, 0, stream>>>(predw, fullw, sumeff, sumatt, out);
}

// Round 4
// 1372.022 us; speedup vs baseline: 1.6201x; 1.6201x over previous
//
#include <hip/hip_runtime.h>
#include <math.h>
#include <stdint.h>

#define B_ 8
#define T_ 2048
#define D_ 1024
#define H_ 1365
#define NTOK (B_*T_)
#define NSAMP 5
#define NRHO 5

#define TILE_T 128
#define TILE_H 128
#define KC 16

// ---- ws layout (bytes) ----
#define WS_SCORES 0                              // f64 [16384]
#define WS_CNT    (WS_SCORES + NTOK*8)           // int [5*8*2048]
#define WS_PREDW  (WS_CNT + NRHO*B_*T_*4)        // f64 [5][8][1024]
#define WS_FULLW  (WS_PREDW + NRHO*B_*D_*8)      // f64 [8][1024]
#define WS_SUMEFF (WS_FULLW + B_*D_*8)           // f64 [5][8]
#define WS_SUMATT (WS_SUMEFF + NRHO*B_*8)        // f64 [8]
#define WS_SUMG   (WS_SUMATT + B_*8)             // f64 [5][8]
#define WS_ZERO_BYTES (WS_SUMG + NRHO*B_*8)

// ---- out layout (f32 elements) ----
#define OUT_G      0
#define OUT_GSW    16384
#define OUT_RECON  98304
#define OUT_LOSS   98305
#define OUT_RHOEFF 98310

// ============================================================
// Kernel A: fused LN + GEMM(D->H) + GELU + dot(W2) -> scores (f64 atomics)
// f32 VALU GEMM: 128 tok x 128 h tile, 8x8 per thread, KC=16.
// LN stats f64 (R1-proven); epilogue gelu/W2-dot f64.
// Rank-safety: f32 GEMM error ~1e-7 << ~5e-3 threshold gaps (np ref is f32;
// jax-f32 vs np-f32 cross-check passes => f32-class rounding is safe).
// ============================================================
__launch_bounds__(256)
__global__ void k_scores(const float* __restrict__ emb, const float* __restrict__ attn,
                         const float* __restrict__ ln_g, const float* __restrict__ ln_b,
                         const float* __restrict__ W1, const float* __restrict__ b1,
                         const float* __restrict__ W2, double* __restrict__ scores)
{
    __shared__ float  sA[KC][132];      // [k][tok], stride 132 => 16B-aligned rows
    __shared__ float  sB[KC][132];      // [k][h]
    __shared__ double sM[TILE_T], sI[TILE_T];
    __shared__ double sRed[TILE_T][17]; // [tok][tx], padded

    const int tid = threadIdx.x;
    const int t0  = blockIdx.y * TILE_T;   // token block
    const int h0  = blockIdx.x * TILE_H;   // h block
    const int l   = tid & 63, w = tid >> 6;
    const int tx  = tid & 15, ty = tid >> 4;

    // ---- LN stats for 128 tokens (f64, identical numerics to R1) ----
    for (int tk = w; tk < TILE_T; tk += 4) {
        const int tg = t0 + tk;
        const float av = attn[tg];
        const float* row = emb + (size_t)tg * D_;
        double s1 = 0.0, s2 = 0.0;
        #pragma unroll
        for (int i = 0; i < D_/64; ++i) {
            double x = (double)row[i*64 + l] * (double)av;
            s1 += x; s2 += x * x;
        }
        for (int m = 32; m; m >>= 1) { s1 += __shfl_xor(s1, m); s2 += __shfl_xor(s2, m); }
        if (l == 0) {
            double mean = s1 / (double)D_;
            double var  = s2 / (double)D_ - mean * mean;
            sM[tk] = mean;
            sI[tk] = 1.0 / sqrt(var + 1e-5);
        }
    }
    __syncthreads();

    float acc[8][8];
    #pragma unroll
    for (int i = 0; i < 8; ++i)
        #pragma unroll
        for (int j = 0; j < 8; ++j) acc[i][j] = 0.0f;

    for (int kc = 0; kc < D_; kc += KC) {
        // stage W1 tile [k][h] — h fast => coalesced
        #pragma unroll
        for (int r = 0; r < 8; ++r) {
            int e = tid + r * 256;
            int k = e >> 7, hh = e & 127;
            int hg = h0 + hh;
            sB[k][hh] = (hg < H_) ? W1[(size_t)(kc + k) * H_ + hg] : 0.0f;
        }
        // stage LN(A) tile [k][tok] — k fast => 16-float contiguous runs
        #pragma unroll
        for (int r = 0; r < 8; ++r) {
            int e = tid + r * 256;
            int k = e & 15, tk = e >> 4;
            int tg = t0 + tk, dg = kc + k;
            double x  = (double)emb[(size_t)tg * D_ + dg] * (double)attn[tg];
            double xn = (x - sM[tk]) * sI[tk] * (double)ln_g[dg] + (double)ln_b[dg];
            sA[k][tk] = (float)xn;
        }
        __syncthreads();
        #pragma unroll
        for (int k = 0; k < KC; ++k) {
            float av[8], wv[8];
            *(float4*)&av[0] = *(const float4*)&sA[k][ty * 8];
            *(float4*)&av[4] = *(const float4*)&sA[k][ty * 8 + 4];
            *(float4*)&wv[0] = *(const float4*)&sB[k][tx * 8];
            *(float4*)&wv[4] = *(const float4*)&sB[k][tx * 8 + 4];
            #pragma unroll
            for (int i = 0; i < 8; ++i)
                #pragma unroll
                for (int j = 0; j < 8; ++j)
                    acc[i][j] = fmaf(av[i], wv[j], acc[i][j]);
        }
        __syncthreads();
    }

    // ---- epilogue: gelu(z + b1) * W2 in f64, reduce over h, atomic add ----
    const double inv_sqrt2 = 0.70710678118654752440;
    #pragma unroll
    for (int i = 0; i < 8; ++i) {
        double s = 0.0;
        #pragma unroll
        for (int j = 0; j < 8; ++j) {
            int hg = h0 + tx * 8 + j;
            if (hg < H_) {
                double z  = (double)acc[i][j] + (double)b1[hg];
                double gl = 0.5 * z * (1.0 + erf(z * inv_sqrt2));
                s += gl * (double)W2[hg];
            }
        }
        sRed[ty * 8 + i][tx] = s;
    }
    __syncthreads();
    if (tid < TILE_T) {
        double s = 0.0;
        #pragma unroll
        for (int x = 0; x < 16; ++x) s += sRed[tid][x];
        atomicAdd(&scores[t0 + tid], s);
    }
}

// ============================================================
// JAX threefry2x32 (matches jax._src.prng exactly)
// ============================================================
__device__ inline void tf2x32(uint32_t k0, uint32_t k1, uint32_t x0, uint32_t x1,
                              uint32_t& o0, uint32_t& o1)
{
    const uint32_t ks2 = k0 ^ k1 ^ 0x1BD11BDAu;
    x0 += k0; x1 += k1;
#define ROT_(v,d) (((v) << (d)) | ((v) >> (32 - (d))))
#define RND_(R) { x0 += x1; x1 = ROT_(x1, R); x1 ^= x0; }
    RND_(13) RND_(15) RND_(26) RND_(6)
    x0 += k1;  x1 += ks2 + 1u;
    RND_(17) RND_(29) RND_(16) RND_(24)
    x0 += ks2; x1 += k0 + 2u;
    RND_(13) RND_(15) RND_(26) RND_(6)
    x0 += k0;  x1 += k1 + 3u;
    RND_(17) RND_(29) RND_(16) RND_(24)
    x0 += k1;  x1 += ks2 + 4u;
    RND_(13) RND_(15) RND_(26) RND_(6)
    x0 += ks2; x1 += k0 + 5u;
    o0 = x0; o1 = x1;
#undef RND_
#undef ROT_
}

// ============================================================
// Kernel B: per (rho j, sample s, batch b): gumbel pert + bitonic sort +
//           k-th threshold + indicator count accumulation
// RNG: jax_threefry_partitionable=True stream (verified passing in R2 bench of R1 kernel)
// ============================================================
__launch_bounds__(256)
__global__ void k_topk(const double* __restrict__ scores, const float* __restrict__ attn,
                       const float* __restrict__ b2, int* __restrict__ cnt)
{
    __shared__ double pertO[2048];
    __shared__ double psort[2048];
    __shared__ double red[4];

    const int tid = threadIdx.x;
    const int blk = blockIdx.x;
    const int j = blk / 40;
    const int s = (blk % 40) >> 3;
    const int b = blk & 7;

    uint32_t kk0, kk1;
    tf2x32(0u, 42u, 0u, (uint32_t)j, kk0, kk1);

    double tsum = 0.0;
    for (int t = tid; t < T_; t += 256) tsum += (double)attn[b * T_ + t];
    for (int m = 32; m; m >>= 1) tsum += __shfl_xor(tsum, m);
    if ((tid & 63) == 0) red[tid >> 6] = tsum;
    __syncthreads();
    const double Teff = red[0] + red[1] + red[2] + red[3];
    const float rhos[5] = {0.1f, 0.2f, 0.3f, 0.4f, 0.5f};
    int kst = (int)(rhos[j] * (float)Teff);
    if (kst < 1) kst = 1;

    const double bb2 = (double)b2[0];
    for (int t = tid; t < T_; t += 256) {
        int f = (s * 8 + b) * T_ + t;
        uint32_t o0, o1;
        tf2x32(kk0, kk1, 0u, (uint32_t)f, o0, o1);
        uint32_t bits = o0 ^ o1;
        float u = __uint_as_float((bits >> 9) | 0x3f800000u) - 1.0f;
        float a1 = (float)((double)u + (double)1e-6f);
        float la = (float)log((double)a1);
        float m1 = (float)((double)1e-6f - (double)la);
        float lb = (float)log((double)m1);
        float noise = -lb;
        float av = attn[b * T_ + t];
        double pv = (av == 0.0f) ? -1e9 : (scores[b * T_ + t] + bb2 + (double)noise);
        pertO[t] = pv;
        psort[t] = pv;
    }
    __syncthreads();

    for (int size = 2; size <= 2048; size <<= 1) {
        for (int stride = size >> 1; stride > 0; stride >>= 1) {
            for (int i = tid; i < 2048; i += 256) {
                int lix = i ^ stride;
                if (lix > i) {
                    double x = psort[i], y = psort[lix];
                    bool asc = ((i & size) == 0);
                    if ((x > y) == asc) { psort[i] = y; psort[lix] = x; }
                }
            }
            __syncthreads();
        }
    }
    const double thr = psort[2048 - kst];
    for (int t = tid; t < T_; t += 256) {
        if (pertO[t] >= thr) atomicAdd(&cnt[(j * 8 + b) * T_ + t], 1);
    }
}

// ============================================================
// Kernel C: finalize g = cnt/5, write g & g_sweep & rho_eff, row sums
// ============================================================
__launch_bounds__(256)
__global__ void k_gfin(const int* __restrict__ cnt, const float* __restrict__ attn,
                       float* __restrict__ out, double* __restrict__ sumeff,
                       double* __restrict__ sumatt, double* __restrict__ sumg)
{
    __shared__ double redA[4], redB[4], redC[4];
    const int j = blockIdx.x >> 3, b = blockIdx.x & 7;
    const int tid = threadIdx.x;
    double sg = 0.0, se = 0.0, sa = 0.0;
    for (int t = tid; t < T_; t += 256) {
        int c = cnt[(j * 8 + b) * T_ + t];
        float g  = (float)c / 5.0f;
        float av = attn[b * T_ + t];
        out[OUT_GSW + (j * 8 + b) * T_ + t] = g;
        if (j == 4) out[OUT_G + b * T_ + t] = g;
        sg += (double)g;
        se += (double)(av * g);
        sa += (double)av;
    }
    for (int m = 32; m; m >>= 1) { sg += __shfl_xor(sg, m); se += __shfl_xor(se, m); sa += __shfl_xor(sa, m); }
    if ((tid & 63) == 0) { redA[tid>>6] = sg; redB[tid>>6] = se; redC[tid>>6] = sa; }
    __syncthreads();
    if (tid == 0) {
        sg = redA[0]+redA[1]+redA[2]+redA[3];
        se = redB[0]+redB[1]+redB[2]+redB[3];
        sa = redC[0]+redC[1]+redC[2]+redC[3];
        sumg[j*8+b] = sg; sumeff[j*8+b] = se;
        if (j == 0) sumatt[b] = sa;
        out[OUT_RHOEFF + j*8 + b] = (float)sg / (float)sa;
    }
}

// ============================================================
// Kernel D: pooled weighted sums over tok = emb_table[ids]
// ============================================================
__launch_bounds__(256)
__global__ void k_pool(const int* __restrict__ ids, const float* __restrict__ attn,
                       const float* __restrict__ out, const float* __restrict__ emb_table,
                       double* __restrict__ predw, double* __restrict__ fullw)
{
    __shared__ int   sid[256];
    __shared__ float sw[6][256];
    const int blk = blockIdx.x;
    const int b  = blk >> 5;
    const int dc = (blk >> 3) & 3;
    const int tc = blk & 7;
    const int tid = threadIdx.x;
    const int d = dc * 256 + tid;
    {
        int t = tc * 256 + tid;
        sid[tid] = ids[b * T_ + t];
        float av = attn[b * T_ + t];
        sw[0][tid] = av;
        #pragma unroll
        for (int j = 0; j < 5; ++j) {
            float g = out[OUT_GSW + (j * 8 + b) * T_ + t];
            sw[1 + j][tid] = av * g;
        }
    }
    __syncthreads();
    double acc[6] = {0,0,0,0,0,0};
    for (int i = 0; i < 256; ++i) {
        float val = emb_table[(size_t)sid[i] * D_ + d];
        #pragma unroll
        for (int c = 0; c < 6; ++c) acc[c] += (double)(val * sw[c][i]);
    }
    atomicAdd(&fullw[b * D_ + d], acc[0]);
    #pragma unroll
    for (int j = 0; j < 5; ++j)
        atomicAdd(&predw[(j * 8 + b) * D_ + d], acc[1 + j]);
}

// ============================================================
// Kernel E: losses (single block)
// ============================================================
__launch_bounds__(256)
__global__ void k_loss(const double* __restrict__ predw, const double* __restrict__ fullw,
                       const double* __restrict__ sumeff, const double* __restrict__ sumatt,
                       float* __restrict__ out)
{
    __shared__ double red[4];
    __shared__ float lr[5];
    const int tid = threadIdx.x;
    for (int j = 0; j < 5; ++j) {
        double p = 0.0;
        for (int i = tid; i < B_ * D_; i += 256) {
            int b = i >> 10;
            double dF = sumatt[b];        if (dF < 1e-6) dF = 1e-6;
            double dE = sumeff[j*8 + b];  if (dE < 1e-6) dE = 1e-6;
            double diff = predw[j * B_ * D_ + i] / dE - fullw[i] / dF;
            p += diff * diff;
        }
        for (int m = 32; m; m >>= 1) p += __shfl_xor(p, m);
        if ((tid & 63) == 0) red[tid >> 6] = p;
        __syncthreads();
        if (tid == 0) {
            double t = red[0] + red[1] + red[2] + red[3];
            lr[j] = (float)(t / (double)(B_ * D_));
            out[OUT_LOSS + j] = lr[j];
        }
        __syncthreads();
    }
    if (tid == 0) {
        float srec = 0.0f;
        for (int j = 0; j < 5; ++j) srec += lr[j];
        out[OUT_RECON] = srec / 5.0f;
    }
}

extern "C" void kernel_launch(void* const* d_in, const int* in_sizes, int n_in,
                              void* d_out, int out_size, void* d_ws, size_t ws_size,
                              hipStream_t stream)
{
    const int*   ids  = (const int*)  d_in[0];
    const float* emb  = (const float*)d_in[1];
    const float* attn = (const float*)d_in[2];
    const float* ln_g = (const float*)d_in[3];
    const float* ln_b = (const float*)d_in[4];
    const float* W1   = (const float*)d_in[5];
    const float* b1   = (const float*)d_in[6];
    const float* W2   = (const float*)d_in[7];
    const float* b2   = (const float*)d_in[8];
    const float* et   = (const float*)d_in[9];
    float* out = (float*)d_out;
    char*  ws  = (char*)d_ws;

    double* scores = (double*)(ws + WS_SCORES);
    int*    cnt    = (int*)   (ws + WS_CNT);
    double* predw  = (double*)(ws + WS_PREDW);
    double* fullw  = (double*)(ws + WS_FULLW);
    double* sumeff = (double*)(ws + WS_SUMEFF);
    double* sumatt = (double*)(ws + WS_SUMATT);
    double* sumg   = (double*)(ws + WS_SUMG);

    hipMemsetAsync(d_ws, 0, WS_ZERO_BYTES, stream);

    dim3 gA(11, 128);   // 11 h-blocks (11*128=1408>=1365) x 128 token-blocks
    k_scores<<<gA, 256, 0, stream>>>(emb, attn, ln_g, ln_b, W1, b1, W2, scores);
    k_topk<<<NRHO * NSAMP * B_, 256, 0, stream>>>(scores, attn, b2, cnt);
    k_gfin<<<NRHO * B_, 256, 0, stream>>>(cnt, attn, out, sumeff, sumatt, sumg);
    k_pool<<<256, 256, 0, stream>>>(ids, attn, out, et, predw, fullw);
    k_loss<<<1, 256, 0, stream>>>(predw, fullw, sumeff, sumatt, out);
}

// Round 5
// 617.436 us; speedup vs baseline: 3.6001x; 2.2221x over previous
//
#include <hip/hip_runtime.h>
#include <math.h>
#include <stdint.h>

#define B_ 8
#define T_ 2048
#define D_ 1024
#define H_ 1365
#define HPAD 1408
#define NTOK (B_*T_)
#define NSAMP 5
#define NRHO 5

typedef float  f32x4  __attribute__((ext_vector_type(4)));
typedef __bf16 bf16x8 __attribute__((ext_vector_type(8)));

// ---- ws layout (bytes) ----
#define WS_SCORES 0                              // f64 [16384]
#define WS_CNT    (WS_SCORES + NTOK*8)           // int [5*8*2048]
#define WS_PREDW  (WS_CNT + NRHO*B_*T_*4)        // f64 [5][8][1024]
#define WS_FULLW  (WS_PREDW + NRHO*B_*D_*8)      // f64 [8][1024]
#define WS_SUMEFF (WS_FULLW + B_*D_*8)           // f64 [5][8]
#define WS_SUMATT (WS_SUMEFF + NRHO*B_*8)        // f64 [8]
#define WS_SUMG   (WS_SUMATT + B_*8)             // f64 [5][8]
#define WS_ZERO_BYTES (WS_SUMG + NRHO*B_*8)
#define WS_STATS  (WS_SUMG + NRHO*B_*8)          // float2 [16384] (scale, shift)
#define WS_W1THI  (WS_STATS + NTOK*8)            // ushort [1408][1024]
#define WS_W1TLO  (WS_W1THI + HPAD*D_*2)         // ushort [1408][1024]

// ---- out layout (f32 elements) ----
#define OUT_G      0
#define OUT_GSW    16384
#define OUT_RECON  98304
#define OUT_LOSS   98305
#define OUT_RHOEFF 98310

__device__ inline unsigned short f2bf(float x) {   // RNE f32 -> bf16 bits
    uint32_t u = __float_as_uint(x);
    return (unsigned short)((u + 0x7FFFu + ((u >> 16) & 1u)) >> 16);
}

// ============================================================
// Prep 1: per-token LN stats (f64, R1-proven numerics) -> (av*inv, mean*inv) f32
// ============================================================
__launch_bounds__(256)
__global__ void k_stats(const float* __restrict__ emb, const float* __restrict__ attn,
                        float2* __restrict__ stats)
{
    const int tid = threadIdx.x, l = tid & 63, w = tid >> 6;
    const int t0 = blockIdx.x * 64;
    for (int tk = w; tk < 64; tk += 4) {
        const int tg = t0 + tk;
        const float av = attn[tg];
        const float* row = emb + (size_t)tg * D_;
        double s1 = 0.0, s2 = 0.0;
        #pragma unroll
        for (int i = 0; i < D_/64; ++i) {
            double x = (double)row[i*64 + l] * (double)av;
            s1 += x; s2 += x * x;
        }
        for (int m = 32; m; m >>= 1) { s1 += __shfl_xor(s1, m); s2 += __shfl_xor(s2, m); }
        if (l == 0) {
            double mean = s1 / (double)D_;
            double var  = s2 / (double)D_ - mean * mean;
            double inv  = 1.0 / sqrt(var + 1e-5);
            stats[tg] = make_float2((float)((double)av * inv), (float)(mean * inv));
        }
    }
}

// ============================================================
// Prep 2: W1 [1024][1365] -> W1T hi/lo bf16 [1408][1024] (k-contiguous)
// ============================================================
__launch_bounds__(256)
__global__ void k_w1t(const float* __restrict__ W1, unsigned short* __restrict__ hi,
                      unsigned short* __restrict__ lo)
{
    __shared__ float tile[32][33];
    const int tid = threadIdx.x;
    const int bk = blockIdx.x & 31;    // 32 k-tiles
    const int bh = blockIdx.x >> 5;    // 44 h-tiles
    const int k0 = bk * 32, h0 = bh * 32;
    const int a = tid & 31, b = tid >> 5;   // b: 0..7
    #pragma unroll
    for (int i = 0; i < 4; ++i) {
        int k = k0 + b + i * 8;
        int h = h0 + a;
        tile[b + i*8][a] = (h < H_) ? W1[(size_t)k * H_ + h] : 0.0f;
    }
    __syncthreads();
    #pragma unroll
    for (int i = 0; i < 4; ++i) {
        int hrow = h0 + b + i * 8;
        int kcol = k0 + a;
        float v = tile[a][b + i*8];      // = W1[kcol][hrow]
        unsigned short hb = f2bf(v);
        float hf = __uint_as_float((uint32_t)hb << 16);
        unsigned short lb = f2bf(v - hf);
        size_t dst = (size_t)hrow * D_ + kcol;
        hi[dst] = hb; lo[dst] = lb;
    }
}

// ============================================================
// Kernel A: LN(bf16-split) x W1(bf16-split) via 3-term MFMA + GELU + dot(W2)
// tile 128 tok x 128 h; 4 waves, wave tile 64x64 = 4x4 mfma_16x16x32
// A/B LDS: [dim][40] ushort (stride 40 => <=2-way bank conflicts, free)
// XCD swizzle: xcd = blk&7; each XCD gets 16 token-tiles x 11 h-tiles contiguous
// ============================================================
__launch_bounds__(256)
__global__ void k_scores(const float* __restrict__ emb, const float* __restrict__ attn,
                         const float* __restrict__ ln_g, const float* __restrict__ ln_b,
                         const float2* __restrict__ stats,
                         const unsigned short* __restrict__ w1thi,
                         const unsigned short* __restrict__ w1tlo,
                         const float* __restrict__ b1, const float* __restrict__ W2,
                         double* __restrict__ scores)
{
    __shared__ __align__(16) unsigned short sAhi[128*40];
    __shared__ __align__(16) unsigned short sAlo[128*40];
    __shared__ __align__(16) unsigned short sBhi[128*40];
    __shared__ __align__(16) unsigned short sBlo[128*40];
    __shared__ float sS1[128], sS2[128];

    const int tid = threadIdx.x;
    const int blk = blockIdx.x;          // 1408 = 8 xcd * (16 tok-tiles * 11 h-tiles)
    const int xcd = blk & 7, slot = blk >> 3;
    const int lin = xcd * 176 + slot;
    const int tt = lin / 11, hh = lin - tt * 11;
    const int t0 = tt * 128;
    const int h0 = hh * 128;

    if (tid < 128) {
        float2 st = stats[t0 + tid];
        sS1[tid] = st.x; sS2[tid] = st.y;
    }

    f32x4 acc[4][4];
    #pragma unroll
    for (int r = 0; r < 4; ++r)
        #pragma unroll
        for (int c = 0; c < 4; ++c) acc[r][c] = (f32x4){0.f, 0.f, 0.f, 0.f};

    const int l = tid & 63, w = tid >> 6;
    const int lm = l & 15, lq = l >> 4;
    const int wr = (w >> 1) * 64;        // wave token offset
    const int wc = (w & 1) * 64;         // wave h offset
    __syncthreads();

    for (int kc = 0; kc < D_; kc += 32) {
        // ---- stage B: copy W1T hi/lo tiles (k-contiguous bf16x8) ----
        #pragma unroll
        for (int r2 = 0; r2 < 2; ++r2) {
            int g = tid + r2 * 256;
            int row = g >> 2, oct = g & 3;
            size_t src = (size_t)(h0 + row) * D_ + kc + oct * 8;
            int dst = row * 40 + oct * 8;
            *(bf16x8*)&sBhi[dst] = *(const bf16x8*)&w1thi[src];
            *(bf16x8*)&sBlo[dst] = *(const bf16x8*)&w1tlo[src];
        }
        // ---- stage A: LN transform f32 + bf16 hi/lo split ----
        #pragma unroll
        for (int r2 = 0; r2 < 2; ++r2) {
            int g = tid + r2 * 256;
            int tk = g >> 2, oct = g & 3;
            int tg = t0 + tk, dg = kc + oct * 8;
            const float* ep = emb + (size_t)tg * D_ + dg;
            float s1 = sS1[tk], ns2 = -sS2[tk];
            union { unsigned short s[8]; bf16x8 v; } hi, lo;
            #pragma unroll
            for (int j = 0; j < 8; ++j) {
                float t  = fmaf(ep[j], s1, ns2);
                float xn = fmaf(t, ln_g[dg + j], ln_b[dg + j]);
                unsigned short hb = f2bf(xn);
                float hf = __uint_as_float((uint32_t)hb << 16);
                hi.s[j] = hb;
                lo.s[j] = f2bf(xn - hf);
            }
            int dst = tk * 40 + oct * 8;
            *(bf16x8*)&sAhi[dst] = hi.v;
            *(bf16x8*)&sAlo[dst] = lo.v;
        }
        __syncthreads();
        // ---- fragments + 3-term MFMA ----
        bf16x8 ah[4], al[4], bh[4], bl[4];
        #pragma unroll
        for (int r = 0; r < 4; ++r) {
            int off = (wr + r * 16 + lm) * 40 + lq * 8;
            ah[r] = *(const bf16x8*)&sAhi[off];
            al[r] = *(const bf16x8*)&sAlo[off];
        }
        #pragma unroll
        for (int c = 0; c < 4; ++c) {
            int off = (wc + c * 16 + lm) * 40 + lq * 8;
            bh[c] = *(const bf16x8*)&sBhi[off];
            bl[c] = *(const bf16x8*)&sBlo[off];
        }
        #pragma unroll
        for (int r = 0; r < 4; ++r)
            #pragma unroll
            for (int c = 0; c < 4; ++c) {
                acc[r][c] = __builtin_amdgcn_mfma_f32_16x16x32_bf16(ah[r], bh[c], acc[r][c], 0, 0, 0);
                acc[r][c] = __builtin_amdgcn_mfma_f32_16x16x32_bf16(ah[r], bl[c], acc[r][c], 0, 0, 0);
                acc[r][c] = __builtin_amdgcn_mfma_f32_16x16x32_bf16(al[r], bh[c], acc[r][c], 0, 0, 0);
            }
        __syncthreads();
    }

    // ---- epilogue: z = acc + b1; gelu f32; * W2; f64 reduce; atomic ----
    float b1v[4], w2v[4];
    #pragma unroll
    for (int c = 0; c < 4; ++c) {
        int hg = h0 + wc + c * 16 + lm;
        bool ok = (hg < H_);
        b1v[c] = ok ? b1[hg] : 0.0f;
        w2v[c] = ok ? W2[hg] : 0.0f;   // pad cols: acc=0, w2=0 => contribute 0
    }
    const float is2 = 0.70710678118654752440f;
    #pragma unroll
    for (int r = 0; r < 4; ++r) {
        #pragma unroll
        for (int i = 0; i < 4; ++i) {
            float ps = 0.0f;
            #pragma unroll
            for (int c = 0; c < 4; ++c) {
                float z  = acc[r][c][i] + b1v[c];
                float gl = 0.5f * z * (1.0f + erff(z * is2));
                ps = fmaf(gl, w2v[c], ps);
            }
            double psd = (double)ps;
            psd += __shfl_xor(psd, 1);
            psd += __shfl_xor(psd, 2);
            psd += __shfl_xor(psd, 4);
            psd += __shfl_xor(psd, 8);
            if (lm == 0)
                atomicAdd(&scores[t0 + wr + r * 16 + lq * 4 + i], psd);
        }
    }
}

// ============================================================
// JAX threefry2x32 (matches jax._src.prng exactly)
// ============================================================
__device__ inline void tf2x32(uint32_t k0, uint32_t k1, uint32_t x0, uint32_t x1,
                              uint32_t& o0, uint32_t& o1)
{
    const uint32_t ks2 = k0 ^ k1 ^ 0x1BD11BDAu;
    x0 += k0; x1 += k1;
#define ROT_(v,d) (((v) << (d)) | ((v) >> (32 - (d))))
#define RND_(R) { x0 += x1; x1 = ROT_(x1, R); x1 ^= x0; }
    RND_(13) RND_(15) RND_(26) RND_(6)
    x0 += k1;  x1 += ks2 + 1u;
    RND_(17) RND_(29) RND_(16) RND_(24)
    x0 += ks2; x1 += k0 + 2u;
    RND_(13) RND_(15) RND_(26) RND_(6)
    x0 += k0;  x1 += k1 + 3u;
    RND_(17) RND_(29) RND_(16) RND_(24)
    x0 += k1;  x1 += ks2 + 4u;
    RND_(13) RND_(15) RND_(26) RND_(6)
    x0 += ks2; x1 += k0 + 5u;
    o0 = x0; o1 = x1;
#undef RND_
#undef ROT_
}

// ============================================================
// Kernel B: per (rho j, sample s, batch b): gumbel pert + bitonic sort +
//           k-th threshold + indicator count accumulation
// RNG: jax_threefry_partitionable=True stream (verified)
// ============================================================
__launch_bounds__(256)
__global__ void k_topk(const double* __restrict__ scores, const float* __restrict__ attn,
                       const float* __restrict__ b2, int* __restrict__ cnt)
{
    __shared__ double pertO[2048];
    __shared__ double psort[2048];
    __shared__ double red[4];

    const int tid = threadIdx.x;
    const int blk = blockIdx.x;
    const int j = blk / 40;
    const int s = (blk % 40) >> 3;
    const int b = blk & 7;

    uint32_t kk0, kk1;
    tf2x32(0u, 42u, 0u, (uint32_t)j, kk0, kk1);

    double tsum = 0.0;
    for (int t = tid; t < T_; t += 256) tsum += (double)attn[b * T_ + t];
    for (int m = 32; m; m >>= 1) tsum += __shfl_xor(tsum, m);
    if ((tid & 63) == 0) red[tid >> 6] = tsum;
    __syncthreads();
    const double Teff = red[0] + red[1] + red[2] + red[3];
    const float rhos[5] = {0.1f, 0.2f, 0.3f, 0.4f, 0.5f};
    int kst = (int)(rhos[j] * (float)Teff);
    if (kst < 1) kst = 1;

    const double bb2 = (double)b2[0];
    for (int t = tid; t < T_; t += 256) {
        int f = (s * 8 + b) * T_ + t;
        uint32_t o0, o1;
        tf2x32(kk0, kk1, 0u, (uint32_t)f, o0, o1);
        uint32_t bits = o0 ^ o1;
        float u = __uint_as_float((bits >> 9) | 0x3f800000u) - 1.0f;
        float a1 = (float)((double)u + (double)1e-6f);
        float la = (float)log((double)a1);
        float m1 = (float)((double)1e-6f - (double)la);
        float lb = (float)log((double)m1);
        float noise = -lb;
        float av = attn[b * T_ + t];
        double pv = (av == 0.0f) ? -1e9 : (scores[b * T_ + t] + bb2 + (double)noise);
        pertO[t] = pv;
        psort[t] = pv;
    }
    __syncthreads();

    for (int size = 2; size <= 2048; size <<= 1) {
        for (int stride = size >> 1; stride > 0; stride >>= 1) {
            for (int i = tid; i < 2048; i += 256) {
                int lix = i ^ stride;
                if (lix > i) {
                    double x = psort[i], y = psort[lix];
                    bool asc = ((i & size) == 0);
                    if ((x > y) == asc) { psort[i] = y; psort[lix] = x; }
                }
            }
            __syncthreads();
        }
    }
    const double thr = psort[2048 - kst];
    for (int t = tid; t < T_; t += 256) {
        if (pertO[t] >= thr) atomicAdd(&cnt[(j * 8 + b) * T_ + t], 1);
    }
}

// ============================================================
// Kernel C: finalize g = cnt/5, write g & g_sweep & rho_eff, row sums
// ============================================================
__launch_bounds__(256)
__global__ void k_gfin(const int* __restrict__ cnt, const float* __restrict__ attn,
                       float* __restrict__ out, double* __restrict__ sumeff,
                       double* __restrict__ sumatt, double* __restrict__ sumg)
{
    __shared__ double redA[4], redB[4], redC[4];
    const int j = blockIdx.x >> 3, b = blockIdx.x & 7;
    const int tid = threadIdx.x;
    double sg = 0.0, se = 0.0, sa = 0.0;
    for (int t = tid; t < T_; t += 256) {
        int c = cnt[(j * 8 + b) * T_ + t];
        float g  = (float)c / 5.0f;
        float av = attn[b * T_ + t];
        out[OUT_GSW + (j * 8 + b) * T_ + t] = g;
        if (j == 4) out[OUT_G + b * T_ + t] = g;
        sg += (double)g;
        se += (double)(av * g);
        sa += (double)av;
    }
    for (int m = 32; m; m >>= 1) { sg += __shfl_xor(sg, m); se += __shfl_xor(se, m); sa += __shfl_xor(sa, m); }
    if ((tid & 63) == 0) { redA[tid>>6] = sg; redB[tid>>6] = se; redC[tid>>6] = sa; }
    __syncthreads();
    if (tid == 0) {
        sg = redA[0]+redA[1]+redA[2]+redA[3];
        se = redB[0]+redB[1]+redB[2]+redB[3];
        sa = redC[0]+redC[1]+redC[2]+redC[3];
        sumg[j*8+b] = sg; sumeff[j*8+b] = se;
        if (j == 0) sumatt[b] = sa;
        out[OUT_RHOEFF + j*8 + b] = (float)sg / (float)sa;
    }
}

// ============================================================
// Kernel D: pooled weighted sums over tok = emb_table[ids]
// ============================================================
__launch_bounds__(256)
__global__ void k_pool(const int* __restrict__ ids, const float* __restrict__ attn,
                       const float* __restrict__ out, const float* __restrict__ emb_table,
                       double* __restrict__ predw, double* __restrict__ fullw)
{
    __shared__ int   sid[256];
    __shared__ float sw[6][256];
    const int blk = blockIdx.x;
    const int b  = blk >> 5;
    const int dc = (blk >> 3) & 3;
    const int tc = blk & 7;
    const int tid = threadIdx.x;
    const int d = dc * 256 + tid;
    {
        int t = tc * 256 + tid;
        sid[tid] = ids[b * T_ + t];
        float av = attn[b * T_ + t];
        sw[0][tid] = av;
        #pragma unroll
        for (int j = 0; j < 5; ++j) {
            float g = out[OUT_GSW + (j * 8 + b) * T_ + t];
            sw[1 + j][tid] = av * g;
        }
    }
    __syncthreads();
    double acc[6] = {0,0,0,0,0,0};
    for (int i = 0; i < 256; ++i) {
        float val = emb_table[(size_t)sid[i] * D_ + d];
        #pragma unroll
        for (int c = 0; c < 6; ++c) acc[c] += (double)(val * sw[c][i]);
    }
    atomicAdd(&fullw[b * D_ + d], acc[0]);
    #pragma unroll
    for (int j = 0; j < 5; ++j)
        atomicAdd(&predw[(j * 8 + b) * D_ + d], acc[1 + j]);
}

// ============================================================
// Kernel E: losses (single block)
// ============================================================
__launch_bounds__(256)
__global__ void k_loss(const double* __restrict__ predw, const double* __restrict__ fullw,
                       const double* __restrict__ sumeff, const double* __restrict__ sumatt,
                       float* __restrict__ out)
{
    __shared__ double red[4];
    __shared__ float lr[5];
    const int tid = threadIdx.x;
    for (int j = 0; j < 5; ++j) {
        double p = 0.0;
        for (int i = tid; i < B_ * D_; i += 256) {
            int b = i >> 10;
            double dF = sumatt[b];        if (dF < 1e-6) dF = 1e-6;
            double dE = sumeff[j*8 + b];  if (dE < 1e-6) dE = 1e-6;
            double diff = predw[j * B_ * D_ + i] / dE - fullw[i] / dF;
            p += diff * diff;
        }
        for (int m = 32; m; m >>= 1) p += __shfl_xor(p, m);
        if ((tid & 63) == 0) red[tid >> 6] = p;
        __syncthreads();
        if (tid == 0) {
            double t = red[0] + red[1] + red[2] + red[3];
            lr[j] = (float)(t / (double)(B_ * D_));
            out[OUT_LOSS + j] = lr[j];
        }
        __syncthreads();
    }
    if (tid == 0) {
        float srec = 0.0f;
        for (int j = 0; j < 5; ++j) srec += lr[j];
        out[OUT_RECON] = srec / 5.0f;
    }
}

extern "C" void kernel_launch(void* const* d_in, const int* in_sizes, int n_in,
                              void* d_out, int out_size, void* d_ws, size_t ws_size,
                              hipStream_t stream)
{
    const int*   ids  = (const int*)  d_in[0];
    const float* emb  = (const float*)d_in[1];
    const float* attn = (const float*)d_in[2];
    const float* ln_g = (const float*)d_in[3];
    const float* ln_b = (const float*)d_in[4];
    const float* W1   = (const float*)d_in[5];
    const float* b1   = (const float*)d_in[6];
    const float* W2   = (const float*)d_in[7];
    const float* b2   = (const float*)d_in[8];
    const float* et   = (const float*)d_in[9];
    float* out = (float*)d_out;
    char*  ws  = (char*)d_ws;

    double* scores = (double*)(ws + WS_SCORES);
    int*    cnt    = (int*)   (ws + WS_CNT);
    double* predw  = (double*)(ws + WS_PREDW);
    double* fullw  = (double*)(ws + WS_FULLW);
    double* sumeff = (double*)(ws + WS_SUMEFF);
    double* sumatt = (double*)(ws + WS_SUMATT);
    double* sumg   = (double*)(ws + WS_SUMG);
    float2* stats  = (float2*)(ws + WS_STATS);
    unsigned short* w1thi = (unsigned short*)(ws + WS_W1THI);
    unsigned short* w1tlo = (unsigned short*)(ws + WS_W1TLO);

    hipMemsetAsync(d_ws, 0, WS_ZERO_BYTES, stream);

    k_stats<<<NTOK/64, 256, 0, stream>>>(emb, attn, stats);
    k_w1t<<<44*32, 256, 0, stream>>>(W1, w1thi, w1tlo);
    k_scores<<<1408, 256, 0, stream>>>(emb, attn, ln_g, ln_b, stats, w1thi, w1tlo,
                                       b1, W2, scores);
    k_topk<<<NRHO * NSAMP * B_, 256, 0, stream>>>(scores, attn, b2, cnt);
    k_gfin<<<NRHO * B_, 256, 0, stream>>>(cnt, attn, out, sumeff, sumatt, sumg);
    k_pool<<<256, 256, 0, stream>>>(ids, attn, out, et, predw, fullw);
    k_loss<<<1, 256, 0, stream>>>(predw, fullw, sumeff, sumatt, out);
}

// Round 6
// 519.269 us; speedup vs baseline: 4.2807x; 1.1890x over previous
//
#include <hip/hip_runtime.h>
#include <math.h>
#include <stdint.h>

#define B_ 8
#define T_ 2048
#define D_ 1024
#define H_ 1365
#define HPAD 1408
#define NTOK (B_*T_)
#define NSAMP 5
#define NRHO 5

typedef float  f32x4  __attribute__((ext_vector_type(4)));
typedef __bf16 bf16x8 __attribute__((ext_vector_type(8)));

// ---- ws layout (bytes) ----
#define WS_SCORES 0                              // f64 [16384]
#define WS_CNT    (WS_SCORES + NTOK*8)           // int [5*8*2048]
#define WS_PREDW  (WS_CNT + NRHO*B_*T_*4)        // f64 [5][8][1024]
#define WS_FULLW  (WS_PREDW + NRHO*B_*D_*8)      // f64 [8][1024]
#define WS_SUMEFF (WS_FULLW + B_*D_*8)           // f64 [5][8]
#define WS_SUMATT (WS_SUMEFF + NRHO*B_*8)        // f64 [8]
#define WS_SUMG   (WS_SUMATT + B_*8)             // f64 [5][8]
#define WS_ZERO_BYTES (WS_SUMG + NRHO*B_*8)
#define WS_STATS  (WS_SUMG + NRHO*B_*8)          // float2 [16384] (fallback path)
#define WS_W1THI  (WS_STATS + NTOK*8)            // ushort [1408][1024]
#define WS_W1TLO  (WS_W1THI + (size_t)HPAD*D_*2) // ushort [1408][1024]
#define WS_AHI    (WS_W1TLO + (size_t)HPAD*D_*2) // ushort [16384][1024]
#define WS_ALO    (WS_AHI + (size_t)NTOK*D_*2)   // ushort [16384][1024]
#define WS_FULL_END (WS_ALO + (size_t)NTOK*D_*2)

// ---- out layout (f32 elements) ----
#define OUT_G      0
#define OUT_GSW    16384
#define OUT_RECON  98304
#define OUT_LOSS   98305
#define OUT_RHOEFF 98310

__device__ inline unsigned short f2bf(float x) {   // RNE f32 -> bf16 bits
    uint32_t u = __float_as_uint(x);
    return (unsigned short)((u + 0x7FFFu + ((u >> 16) & 1u)) >> 16);
}

// ============================================================
// Prep: W1 [1024][1365] -> W1T hi/lo bf16 [1408][1024] (k-contiguous)
// ============================================================
__launch_bounds__(256)
__global__ void k_w1t(const float* __restrict__ W1, unsigned short* __restrict__ hi,
                      unsigned short* __restrict__ lo)
{
    __shared__ float tile[32][33];
    const int tid = threadIdx.x;
    const int bk = blockIdx.x & 31;
    const int bh = blockIdx.x >> 5;
    const int k0 = bk * 32, h0 = bh * 32;
    const int a = tid & 31, b = tid >> 5;
    #pragma unroll
    for (int i = 0; i < 4; ++i) {
        int k = k0 + b + i * 8;
        int h = h0 + a;
        tile[b + i*8][a] = (h < H_) ? W1[(size_t)k * H_ + h] : 0.0f;
    }
    __syncthreads();
    #pragma unroll
    for (int i = 0; i < 4; ++i) {
        int hrow = h0 + b + i * 8;
        int kcol = k0 + a;
        float v = tile[a][b + i*8];
        unsigned short hb = f2bf(v);
        float hf = __uint_as_float((uint32_t)hb << 16);
        unsigned short lb = f2bf(v - hf);
        size_t dst = (size_t)hrow * D_ + kcol;
        hi[dst] = hb; lo[dst] = lb;
    }
}

// ============================================================
// Prep: fused LN stats (f64, R1 numerics) + f32 transform (R4 chain) +
//       bf16 hi/lo split -> Ahi/Alo [16384][1024]
// ============================================================
__launch_bounds__(256)
__global__ void k_asplit(const float* __restrict__ emb, const float* __restrict__ attn,
                         const float* __restrict__ ln_g, const float* __restrict__ ln_b,
                         unsigned short* __restrict__ ahi, unsigned short* __restrict__ alo)
{
    const int tid = threadIdx.x, l = tid & 63, w = tid >> 6;
    const int t0 = blockIdx.x * 64;
    for (int tk = w; tk < 64; tk += 4) {
        const int tg = t0 + tk;
        const float av = attn[tg];
        const float* row = emb + (size_t)tg * D_;
        float rv[16];
        double s1 = 0.0, s2 = 0.0;
        #pragma unroll
        for (int i = 0; i < 16; ++i) {
            rv[i] = row[i*64 + l];
            double x = (double)rv[i] * (double)av;
            s1 += x; s2 += x * x;
        }
        for (int m = 32; m; m >>= 1) { s1 += __shfl_xor(s1, m); s2 += __shfl_xor(s2, m); }
        double mean = s1 / (double)D_;
        double var  = s2 / (double)D_ - mean * mean;
        double inv  = 1.0 / sqrt(var + 1e-5);
        float sc  = (float)((double)av * inv);
        float nsh = -(float)(mean * inv);
        #pragma unroll
        for (int i = 0; i < 16; ++i) {
            int k = i * 64 + l;
            float t  = fmaf(rv[i], sc, nsh);
            float xn = fmaf(t, ln_g[k], ln_b[k]);
            unsigned short hb = f2bf(xn);
            float hf = __uint_as_float((uint32_t)hb << 16);
            size_t dst = (size_t)tg * D_ + k;
            ahi[dst] = hb;
            alo[dst] = f2bf(xn - hf);
        }
    }
}

// (fallback path prep: per-token stats only)
__launch_bounds__(256)
__global__ void k_stats(const float* __restrict__ emb, const float* __restrict__ attn,
                        float2* __restrict__ stats)
{
    const int tid = threadIdx.x, l = tid & 63, w = tid >> 6;
    const int t0 = blockIdx.x * 64;
    for (int tk = w; tk < 64; tk += 4) {
        const int tg = t0 + tk;
        const float av = attn[tg];
        const float* row = emb + (size_t)tg * D_;
        double s1 = 0.0, s2 = 0.0;
        #pragma unroll
        for (int i = 0; i < D_/64; ++i) {
            double x = (double)row[i*64 + l] * (double)av;
            s1 += x; s2 += x * x;
        }
        for (int m = 32; m; m >>= 1) { s1 += __shfl_xor(s1, m); s2 += __shfl_xor(s2, m); }
        if (l == 0) {
            double mean = s1 / (double)D_;
            double var  = s2 / (double)D_ - mean * mean;
            double inv  = 1.0 / sqrt(var + 1e-5);
            stats[tg] = make_float2((float)((double)av * inv), (float)(mean * inv));
        }
    }
}

// ============================================================
// Kernel A (fast): precomputed Ahi/Alo x W1T hi/lo, 3-term MFMA + GELU + W2-dot
// tile 128x128; 4 waves; 4x4 mfma_16x16x32_bf16 per wave; LDS stride 40 (2-way=free)
// ============================================================
__launch_bounds__(256)
__global__ void k_scores(const unsigned short* __restrict__ ahi,
                         const unsigned short* __restrict__ alo,
                         const unsigned short* __restrict__ w1thi,
                         const unsigned short* __restrict__ w1tlo,
                         const float* __restrict__ b1, const float* __restrict__ W2,
                         double* __restrict__ scores)
{
    __shared__ __align__(16) unsigned short sAhi[128*40];
    __shared__ __align__(16) unsigned short sAlo[128*40];
    __shared__ __align__(16) unsigned short sBhi[128*40];
    __shared__ __align__(16) unsigned short sBlo[128*40];

    const int tid = threadIdx.x;
    const int blk = blockIdx.x;          // 1408 = 8 xcd * (16 tok-tiles * 11 h-tiles)
    const int xcd = blk & 7, slot = blk >> 3;
    const int lin = xcd * 176 + slot;
    const int tt = lin / 11, hh = lin - tt * 11;
    const int t0 = tt * 128;
    const int h0 = hh * 128;

    f32x4 acc[4][4];
    #pragma unroll
    for (int r = 0; r < 4; ++r)
        #pragma unroll
        for (int c = 0; c < 4; ++c) acc[r][c] = (f32x4){0.f, 0.f, 0.f, 0.f};

    const int l = tid & 63, w = tid >> 6;
    const int lm = l & 15, lq = l >> 4;
    const int wr = (w >> 1) * 64;
    const int wc = (w & 1) * 64;

    const int row = tid >> 2, oct = tid & 3;
    const int dstoff  = row * 40 + oct * 8;
    const int dstoff2 = (64 + row) * 40 + oct * 8;

    for (int kc = 0; kc < D_; kc += 32) {
        size_t srcA  = (size_t)(t0 + row) * D_ + kc + oct * 8;
        size_t srcA2 = srcA + (size_t)64 * D_;
        size_t srcB  = (size_t)(h0 + row) * D_ + kc + oct * 8;
        size_t srcB2 = srcB + (size_t)64 * D_;
        *(bf16x8*)&sAhi[dstoff]  = *(const bf16x8*)&ahi[srcA];
        *(bf16x8*)&sAlo[dstoff]  = *(const bf16x8*)&alo[srcA];
        *(bf16x8*)&sAhi[dstoff2] = *(const bf16x8*)&ahi[srcA2];
        *(bf16x8*)&sAlo[dstoff2] = *(const bf16x8*)&alo[srcA2];
        *(bf16x8*)&sBhi[dstoff]  = *(const bf16x8*)&w1thi[srcB];
        *(bf16x8*)&sBlo[dstoff]  = *(const bf16x8*)&w1tlo[srcB];
        *(bf16x8*)&sBhi[dstoff2] = *(const bf16x8*)&w1thi[srcB2];
        *(bf16x8*)&sBlo[dstoff2] = *(const bf16x8*)&w1tlo[srcB2];
        __syncthreads();
        bf16x8 ah[4], al[4], bh[4], bl[4];
        #pragma unroll
        for (int r = 0; r < 4; ++r) {
            int off = (wr + r * 16 + lm) * 40 + lq * 8;
            ah[r] = *(const bf16x8*)&sAhi[off];
            al[r] = *(const bf16x8*)&sAlo[off];
        }
        #pragma unroll
        for (int c = 0; c < 4; ++c) {
            int off = (wc + c * 16 + lm) * 40 + lq * 8;
            bh[c] = *(const bf16x8*)&sBhi[off];
            bl[c] = *(const bf16x8*)&sBlo[off];
        }
        #pragma unroll
        for (int r = 0; r < 4; ++r)
            #pragma unroll
            for (int c = 0; c < 4; ++c) {
                acc[r][c] = __builtin_amdgcn_mfma_f32_16x16x32_bf16(ah[r], bh[c], acc[r][c], 0, 0, 0);
                acc[r][c] = __builtin_amdgcn_mfma_f32_16x16x32_bf16(ah[r], bl[c], acc[r][c], 0, 0, 0);
                acc[r][c] = __builtin_amdgcn_mfma_f32_16x16x32_bf16(al[r], bh[c], acc[r][c], 0, 0, 0);
            }
        __syncthreads();
    }

    float b1v[4], w2v[4];
    #pragma unroll
    for (int c = 0; c < 4; ++c) {
        int hg = h0 + wc + c * 16 + lm;
        bool ok = (hg < H_);
        b1v[c] = ok ? b1[hg] : 0.0f;
        w2v[c] = ok ? W2[hg] : 0.0f;
    }
    const float is2 = 0.70710678118654752440f;
    #pragma unroll
    for (int r = 0; r < 4; ++r) {
        #pragma unroll
        for (int i = 0; i < 4; ++i) {
            float ps = 0.0f;
            #pragma unroll
            for (int c = 0; c < 4; ++c) {
                float z  = acc[r][c][i] + b1v[c];
                float gl = 0.5f * z * (1.0f + erff(z * is2));
                ps = fmaf(gl, w2v[c], ps);
            }
            double psd = (double)ps;
            psd += __shfl_xor(psd, 1);
            psd += __shfl_xor(psd, 2);
            psd += __shfl_xor(psd, 4);
            psd += __shfl_xor(psd, 8);
            if (lm == 0)
                atomicAdd(&scores[t0 + wr + r * 16 + lq * 4 + i], psd);
        }
    }
}

// ============================================================
// Kernel A (fallback, R4 version): in-loop LN+split staging
// ============================================================
__launch_bounds__(256)
__global__ void k_scores_fb(const float* __restrict__ emb, const float* __restrict__ ln_g,
                            const float* __restrict__ ln_b, const float2* __restrict__ stats,
                            const unsigned short* __restrict__ w1thi,
                            const unsigned short* __restrict__ w1tlo,
                            const float* __restrict__ b1, const float* __restrict__ W2,
                            double* __restrict__ scores)
{
    __shared__ __align__(16) unsigned short sAhi[128*40];
    __shared__ __align__(16) unsigned short sAlo[128*40];
    __shared__ __align__(16) unsigned short sBhi[128*40];
    __shared__ __align__(16) unsigned short sBlo[128*40];
    __shared__ float sS1[128], sS2[128];

    const int tid = threadIdx.x;
    const int blk = blockIdx.x;
    const int xcd = blk & 7, slot = blk >> 3;
    const int lin = xcd * 176 + slot;
    const int tt = lin / 11, hh = lin - tt * 11;
    const int t0 = tt * 128;
    const int h0 = hh * 128;

    if (tid < 128) {
        float2 st = stats[t0 + tid];
        sS1[tid] = st.x; sS2[tid] = st.y;
    }
    f32x4 acc[4][4];
    #pragma unroll
    for (int r = 0; r < 4; ++r)
        #pragma unroll
        for (int c = 0; c < 4; ++c) acc[r][c] = (f32x4){0.f, 0.f, 0.f, 0.f};
    const int l = tid & 63, w = tid >> 6;
    const int lm = l & 15, lq = l >> 4;
    const int wr = (w >> 1) * 64;
    const int wc = (w & 1) * 64;
    __syncthreads();

    for (int kc = 0; kc < D_; kc += 32) {
        #pragma unroll
        for (int r2 = 0; r2 < 2; ++r2) {
            int g = tid + r2 * 256;
            int row = g >> 2, oct = g & 3;
            size_t src = (size_t)(h0 + row) * D_ + kc + oct * 8;
            int dst = row * 40 + oct * 8;
            *(bf16x8*)&sBhi[dst] = *(const bf16x8*)&w1thi[src];
            *(bf16x8*)&sBlo[dst] = *(const bf16x8*)&w1tlo[src];
        }
        #pragma unroll
        for (int r2 = 0; r2 < 2; ++r2) {
            int g = tid + r2 * 256;
            int tk = g >> 2, oct = g & 3;
            int tg = t0 + tk, dg = kc + oct * 8;
            const float* ep = emb + (size_t)tg * D_ + dg;
            float s1 = sS1[tk], ns2 = -sS2[tk];
            union { unsigned short s[8]; bf16x8 v; } hi, lo;
            #pragma unroll
            for (int j = 0; j < 8; ++j) {
                float t  = fmaf(ep[j], s1, ns2);
                float xn = fmaf(t, ln_g[dg + j], ln_b[dg + j]);
                unsigned short hb = f2bf(xn);
                float hf = __uint_as_float((uint32_t)hb << 16);
                hi.s[j] = hb;
                lo.s[j] = f2bf(xn - hf);
            }
            int dst = tk * 40 + oct * 8;
            *(bf16x8*)&sAhi[dst] = hi.v;
            *(bf16x8*)&sAlo[dst] = lo.v;
        }
        __syncthreads();
        bf16x8 ah[4], al[4], bh[4], bl[4];
        #pragma unroll
        for (int r = 0; r < 4; ++r) {
            int off = (wr + r * 16 + lm) * 40 + lq * 8;
            ah[r] = *(const bf16x8*)&sAhi[off];
            al[r] = *(const bf16x8*)&sAlo[off];
        }
        #pragma unroll
        for (int c = 0; c < 4; ++c) {
            int off = (wc + c * 16 + lm) * 40 + lq * 8;
            bh[c] = *(const bf16x8*)&sBhi[off];
            bl[c] = *(const bf16x8*)&sBlo[off];
        }
        #pragma unroll
        for (int r = 0; r < 4; ++r)
            #pragma unroll
            for (int c = 0; c < 4; ++c) {
                acc[r][c] = __builtin_amdgcn_mfma_f32_16x16x32_bf16(ah[r], bh[c], acc[r][c], 0, 0, 0);
                acc[r][c] = __builtin_amdgcn_mfma_f32_16x16x32_bf16(ah[r], bl[c], acc[r][c], 0, 0, 0);
                acc[r][c] = __builtin_amdgcn_mfma_f32_16x16x32_bf16(al[r], bh[c], acc[r][c], 0, 0, 0);
            }
        __syncthreads();
    }
    float b1v[4], w2v[4];
    #pragma unroll
    for (int c = 0; c < 4; ++c) {
        int hg = h0 + wc + c * 16 + lm;
        bool ok = (hg < H_);
        b1v[c] = ok ? b1[hg] : 0.0f;
        w2v[c] = ok ? W2[hg] : 0.0f;
    }
    const float is2 = 0.70710678118654752440f;
    #pragma unroll
    for (int r = 0; r < 4; ++r) {
        #pragma unroll
        for (int i = 0; i < 4; ++i) {
            float ps = 0.0f;
            #pragma unroll
            for (int c = 0; c < 4; ++c) {
                float z  = acc[r][c][i] + b1v[c];
                float gl = 0.5f * z * (1.0f + erff(z * is2));
                ps = fmaf(gl, w2v[c], ps);
            }
            double psd = (double)ps;
            psd += __shfl_xor(psd, 1);
            psd += __shfl_xor(psd, 2);
            psd += __shfl_xor(psd, 4);
            psd += __shfl_xor(psd, 8);
            if (lm == 0)
                atomicAdd(&scores[t0 + wr + r * 16 + lq * 4 + i], psd);
        }
    }
}

// ============================================================
// JAX threefry2x32
// ============================================================
__device__ inline void tf2x32(uint32_t k0, uint32_t k1, uint32_t x0, uint32_t x1,
                              uint32_t& o0, uint32_t& o1)
{
    const uint32_t ks2 = k0 ^ k1 ^ 0x1BD11BDAu;
    x0 += k0; x1 += k1;
#define ROT_(v,d) (((v) << (d)) | ((v) >> (32 - (d))))
#define RND_(R) { x0 += x1; x1 = ROT_(x1, R); x1 ^= x0; }
    RND_(13) RND_(15) RND_(26) RND_(6)
    x0 += k1;  x1 += ks2 + 1u;
    RND_(17) RND_(29) RND_(16) RND_(24)
    x0 += ks2; x1 += k0 + 2u;
    RND_(13) RND_(15) RND_(26) RND_(6)
    x0 += k0;  x1 += k1 + 3u;
    RND_(17) RND_(29) RND_(16) RND_(24)
    x0 += k1;  x1 += ks2 + 4u;
    RND_(13) RND_(15) RND_(26) RND_(6)
    x0 += ks2; x1 += k0 + 5u;
    o0 = x0; o1 = x1;
#undef RND_
#undef ROT_
}

// ============================================================
// Kernel B: gumbel pert + MSB radix-select k-th largest + indicator counts
// (replaces 66-pass bitonic; threshold semantics identical: thr is the
//  actual key of the k-th largest element, compare key >= thr_key)
// ============================================================
__launch_bounds__(256)
__global__ void k_topk(const double* __restrict__ scores, const float* __restrict__ attn,
                       const float* __restrict__ b2, int* __restrict__ cnt)
{
    __shared__ unsigned long long keys[2048];
    __shared__ unsigned int hist[256];
    __shared__ unsigned int wsum[4];
    __shared__ unsigned int selDigit, selBase;
    __shared__ double red[4];

    const int tid = threadIdx.x;
    const int blk = blockIdx.x;
    const int j = blk / 40;
    const int s = (blk % 40) >> 3;
    const int b = blk & 7;

    uint32_t kk0, kk1;
    tf2x32(0u, 42u, 0u, (uint32_t)j, kk0, kk1);

    double tsum = 0.0;
    for (int t = tid; t < T_; t += 256) tsum += (double)attn[b * T_ + t];
    for (int m = 32; m; m >>= 1) tsum += __shfl_xor(tsum, m);
    if ((tid & 63) == 0) red[tid >> 6] = tsum;
    __syncthreads();
    const double Teff = red[0] + red[1] + red[2] + red[3];
    const float rhos[5] = {0.1f, 0.2f, 0.3f, 0.4f, 0.5f};
    int kst = (int)(rhos[j] * (float)Teff);
    if (kst < 1) kst = 1;

    const double bb2 = (double)b2[0];
    #pragma unroll
    for (int r = 0; r < 8; ++r) {
        int t = tid + r * 256;
        int f = (s * 8 + b) * T_ + t;
        uint32_t o0, o1;
        tf2x32(kk0, kk1, 0u, (uint32_t)f, o0, o1);
        uint32_t bits = o0 ^ o1;
        float u = __uint_as_float((bits >> 9) | 0x3f800000u) - 1.0f;
        float a1 = (float)((double)u + (double)1e-6f);
        float la = (float)log((double)a1);
        float m1 = (float)((double)1e-6f - (double)la);
        float lb = (float)log((double)m1);
        float noise = -lb;
        float av = attn[b * T_ + t];
        double pv = (av == 0.0f) ? -1e9 : (scores[b * T_ + t] + bb2 + (double)noise);
        unsigned long long uu = (unsigned long long)__double_as_longlong(pv);
        keys[t] = (uu >> 63) ? ~uu : (uu | 0x8000000000000000ull);
    }
    __syncthreads();

    // select p-th smallest (ascending), p = 2048 - kst  => k-th largest
    unsigned long long pfx = 0;
    unsigned int plo = (unsigned int)(2048 - kst);
    const int lane = tid & 63, wv = tid >> 6;
    for (int pass = 0; pass < 8; ++pass) {
        const int shift = 56 - 8 * pass;
        const unsigned long long maskhi = (pass == 0) ? 0ull : (~0ull << (64 - 8 * pass));
        hist[tid] = 0;
        __syncthreads();
        #pragma unroll
        for (int r = 0; r < 8; ++r) {
            unsigned long long kk = keys[tid + r * 256];
            if ((kk & maskhi) == pfx)
                atomicAdd(&hist[(unsigned int)((kk >> shift) & 255ull)], 1u);
        }
        __syncthreads();
        unsigned int own = hist[tid];
        int val = (int)own;
        #pragma unroll
        for (int off = 1; off < 64; off <<= 1) {
            int n = __shfl_up(val, off);
            if (lane >= off) val += n;
        }
        if (lane == 63) wsum[wv] = (unsigned int)val;
        __syncthreads();
        unsigned int woff = 0;
        for (int q = 0; q < wv; ++q) woff += wsum[q];
        unsigned int incl = (unsigned int)val + woff;
        unsigned int excl = incl - own;
        if (own > 0 && plo >= excl && plo < incl) { selDigit = (unsigned int)tid; selBase = excl; }
        __syncthreads();
        pfx |= ((unsigned long long)selDigit << shift);
        plo -= selBase;
        __syncthreads();
    }

    #pragma unroll
    for (int r = 0; r < 8; ++r) {
        int t = tid + r * 256;
        if (keys[t] >= pfx) atomicAdd(&cnt[(j * 8 + b) * T_ + t], 1);
    }
}

// ============================================================
// Kernel C: finalize g = cnt/5, write g & g_sweep & rho_eff, row sums
// ============================================================
__launch_bounds__(256)
__global__ void k_gfin(const int* __restrict__ cnt, const float* __restrict__ attn,
                       float* __restrict__ out, double* __restrict__ sumeff,
                       double* __restrict__ sumatt, double* __restrict__ sumg)
{
    __shared__ double redA[4], redB[4], redC[4];
    const int j = blockIdx.x >> 3, b = blockIdx.x & 7;
    const int tid = threadIdx.x;
    double sg = 0.0, se = 0.0, sa = 0.0;
    for (int t = tid; t < T_; t += 256) {
        int c = cnt[(j * 8 + b) * T_ + t];
        float g  = (float)c / 5.0f;
        float av = attn[b * T_ + t];
        out[OUT_GSW + (j * 8 + b) * T_ + t] = g;
        if (j == 4) out[OUT_G + b * T_ + t] = g;
        sg += (double)g;
        se += (double)(av * g);
        sa += (double)av;
    }
    for (int m = 32; m; m >>= 1) { sg += __shfl_xor(sg, m); se += __shfl_xor(se, m); sa += __shfl_xor(sa, m); }
    if ((tid & 63) == 0) { redA[tid>>6] = sg; redB[tid>>6] = se; redC[tid>>6] = sa; }
    __syncthreads();
    if (tid == 0) {
        sg = redA[0]+redA[1]+redA[2]+redA[3];
        se = redB[0]+redB[1]+redB[2]+redB[3];
        sa = redC[0]+redC[1]+redC[2]+redC[3];
        sumg[j*8+b] = sg; sumeff[j*8+b] = se;
        if (j == 0) sumatt[b] = sa;
        out[OUT_RHOEFF + j*8 + b] = (float)sg / (float)sa;
    }
}

// ============================================================
// Kernel D: pooled weighted sums over tok = emb_table[ids] (512 blocks)
// ============================================================
__launch_bounds__(256)
__global__ void k_pool(const int* __restrict__ ids, const float* __restrict__ attn,
                       const float* __restrict__ out, const float* __restrict__ emb_table,
                       double* __restrict__ predw, double* __restrict__ fullw)
{
    __shared__ int   sid[128];
    __shared__ float sw[6][128];
    const int blk = blockIdx.x;
    const int b  = blk >> 6;            // 8
    const int dc = (blk >> 4) & 3;      // 4
    const int tc = blk & 15;            // 16
    const int tid = threadIdx.x;
    const int d = dc * 256 + tid;
    if (tid < 128) {
        int t = tc * 128 + tid;
        sid[tid] = ids[b * T_ + t];
        float av = attn[b * T_ + t];
        sw[0][tid] = av;
        #pragma unroll
        for (int j = 0; j < 5; ++j) {
            float g = out[OUT_GSW + (j * 8 + b) * T_ + t];
            sw[1 + j][tid] = av * g;
        }
    }
    __syncthreads();
    double acc[6] = {0,0,0,0,0,0};
    for (int i = 0; i < 128; ++i) {
        float val = emb_table[(size_t)sid[i] * D_ + d];
        #pragma unroll
        for (int c = 0; c < 6; ++c) acc[c] += (double)(val * sw[c][i]);
    }
    atomicAdd(&fullw[b * D_ + d], acc[0]);
    #pragma unroll
    for (int j = 0; j < 5; ++j)
        atomicAdd(&predw[(j * 8 + b) * D_ + d], acc[1 + j]);
}

// ============================================================
// Kernel E: losses (single block)
// ============================================================
__launch_bounds__(256)
__global__ void k_loss(const double* __restrict__ predw, const double* __restrict__ fullw,
                       const double* __restrict__ sumeff, const double* __restrict__ sumatt,
                       float* __restrict__ out)
{
    __shared__ double red[4];
    __shared__ float lr[5];
    const int tid = threadIdx.x;
    for (int j = 0; j < 5; ++j) {
        double p = 0.0;
        for (int i = tid; i < B_ * D_; i += 256) {
            int b = i >> 10;
            double dF = sumatt[b];        if (dF < 1e-6) dF = 1e-6;
            double dE = sumeff[j*8 + b];  if (dE < 1e-6) dE = 1e-6;
            double diff = predw[j * B_ * D_ + i] / dE - fullw[i] / dF;
            p += diff * diff;
        }
        for (int m = 32; m; m >>= 1) p += __shfl_xor(p, m);
        if ((tid & 63) == 0) red[tid >> 6] = p;
        __syncthreads();
        if (tid == 0) {
            double t = red[0] + red[1] + red[2] + red[3];
            lr[j] = (float)(t / (double)(B_ * D_));
            out[OUT_LOSS + j] = lr[j];
        }
        __syncthreads();
    }
    if (tid == 0) {
        float srec = 0.0f;
        for (int j = 0; j < 5; ++j) srec += lr[j];
        out[OUT_RECON] = srec / 5.0f;
    }
}

extern "C" void kernel_launch(void* const* d_in, const int* in_sizes, int n_in,
                              void* d_out, int out_size, void* d_ws, size_t ws_size,
                              hipStream_t stream)
{
    const int*   ids  = (const int*)  d_in[0];
    const float* emb  = (const float*)d_in[1];
    const float* attn = (const float*)d_in[2];
    const float* ln_g = (const float*)d_in[3];
    const float* ln_b = (const float*)d_in[4];
    const float* W1   = (const float*)d_in[5];
    const float* b1   = (const float*)d_in[6];
    const float* W2   = (const float*)d_in[7];
    const float* b2   = (const float*)d_in[8];
    const float* et   = (const float*)d_in[9];
    float* out = (float*)d_out;
    char*  ws  = (char*)d_ws;

    double* scores = (double*)(ws + WS_SCORES);
    int*    cnt    = (int*)   (ws + WS_CNT);
    double* predw  = (double*)(ws + WS_PREDW);
    double* fullw  = (double*)(ws + WS_FULLW);
    double* sumeff = (double*)(ws + WS_SUMEFF);
    double* sumatt = (double*)(ws + WS_SUMATT);
    double* sumg   = (double*)(ws + WS_SUMG);
    float2* stats  = (float2*)(ws + WS_STATS);
    unsigned short* w1thi = (unsigned short*)(ws + WS_W1THI);
    unsigned short* w1tlo = (unsigned short*)(ws + WS_W1TLO);
    unsigned short* ahi   = (unsigned short*)(ws + WS_AHI);
    unsigned short* alo   = (unsigned short*)(ws + WS_ALO);

    hipMemsetAsync(d_ws, 0, WS_ZERO_BYTES, stream);

    k_w1t<<<44*32, 256, 0, stream>>>(W1, w1thi, w1tlo);
    if (ws_size >= WS_FULL_END) {
        k_asplit<<<NTOK/64, 256, 0, stream>>>(emb, attn, ln_g, ln_b, ahi, alo);
        k_scores<<<1408, 256, 0, stream>>>(ahi, alo, w1thi, w1tlo, b1, W2, scores);
    } else {
        k_stats<<<NTOK/64, 256, 0, stream>>>(emb, attn, stats);
        k_scores_fb<<<1408, 256, 0, stream>>>(emb, ln_g, ln_b, stats, w1thi, w1tlo,
                                              b1, W2, scores);
    }
    k_topk<<<NRHO * NSAMP * B_, 256, 0, stream>>>(scores, attn, b2, cnt);
    k_gfin<<<NRHO * B_, 256, 0, stream>>>(cnt, attn, out, sumeff, sumatt, sumg);
    k_pool<<<512, 256, 0, stream>>>(ids, attn, out, et, predw, fullw);
    k_loss<<<1, 256, 0, stream>>>(predw, fullw, sumeff, sumatt, out);
}